// Round 2
// baseline (163.854 us; speedup 1.0000x reference)
//
#include <hip/hip_runtime.h>
#include <stdint.h>

typedef unsigned short u16;
typedef unsigned int u32;
typedef __attribute__((ext_vector_type(8))) short short8;
typedef __attribute__((ext_vector_type(4))) float float4v;

#define Bb 4
#define Ss 256
#define Hh 768
#define NBASIC 4
#define NALL 64

__device__ __forceinline__ float b2f(u16 h) {
    u32 u = ((u32)h) << 16;
    float f;
    __builtin_memcpy(&f, &u, 4);
    return f;
}
__device__ __forceinline__ u16 f2b(float f) {
    u32 u;
    __builtin_memcpy(&u, &f, 4);
    u = (u + 0x7fffu + ((u >> 16) & 1u)) >> 16;  // RNE
    return (u16)u;
}

// ---- dtype detector: are the float inputs packed bf16 or true fp32? ----
// Low 16 bits of each 32-bit word: for packed bf16 it's a valid bf16 of
// ~N(0,1) (exponent field in [100,140] w.p. ~1); for fp32 it's uniform
// mantissa bits (P ~ 0.16). Count over 256 words separates at >30 sigma.
__global__ __launch_bounds__(256) void k_detect(const u32* __restrict__ hw,
                                                int* __restrict__ flag) {
    __shared__ int cnt;
    if (threadIdx.x == 0) cnt = 0;
    __syncthreads();
    const u32 w = hw[threadIdx.x];
    const int e = (int)((w >> 7) & 0xFFu);  // bf16 exponent field of low half
    atomicAdd(&cnt, (e >= 100 && e <= 140) ? 1 : 0);
    __syncthreads();
    if (threadIdx.x == 0) *flag = (cnt >= 192) ? 1 : 0;  // 1 => bf16 inputs
}

// ---- elementwise normalize to bf16 workspace ----
__global__ __launch_bounds__(256) void k_cvt(const void* __restrict__ src,
                                             u16* __restrict__ dst,
                                             const int* __restrict__ flag, int n) {
    const int i = blockIdx.x * 256 + threadIdx.x;
    if (i >= n) return;
    if (*flag) dst[i] = ((const u16*)src)[i];
    else       dst[i] = f2b(((const float*)src)[i]);
}

// ---- K0: basicT[q][o][i] = basic[q][i][o], normalized to bf16 ----
__global__ __launch_bounds__(256) void k_transpose(const void* __restrict__ basic,
                                                   u16* __restrict__ basicT,
                                                   const int* __restrict__ flag) {
    __shared__ u16 tile[32][33];
    const int q = blockIdx.z;
    const int i0 = blockIdx.y * 32, o0 = blockIdx.x * 32;
    const int tx = threadIdx.x, ty = threadIdx.y;  // 32 x 8
    const int bf = *flag;
    const size_t base = (size_t)q * Hh * Hh;
#pragma unroll
    for (int r = 0; r < 4; ++r) {
        const size_t idx = base + (size_t)(i0 + ty + 8 * r) * Hh + o0 + tx;
        tile[ty + 8 * r][tx] = bf ? ((const u16*)basic)[idx]
                                  : f2b(((const float*)basic)[idx]);
    }
    __syncthreads();
#pragma unroll
    for (int r = 0; r < 4; ++r)
        basicT[base + (size_t)(o0 + ty + 8 * r) * Hh + i0 + tx] = tile[tx][ty + 8 * r];
}

// ---- K1: fused neighbor-count + coefficient + pooled ----
// pooled[b][k][i][:] = sum_j coef_k(i,j) * h[b][j][:]
// coef_k(i,j) = w[f,k]/cnt_f(i) [f=rels[b,i,j]>0] + w[c+32,k]/cnt_c(i) [c=rels[b,j,i]>0]
// one block per (b,i); thread t owns o = t, t+256, t+512
__global__ __launch_bounds__(256) void k_pooled(const u16* __restrict__ h,
                                                const int* __restrict__ rels,
                                                const u16* __restrict__ relw,
                                                u16* __restrict__ pooled) {
    const int i = blockIdx.x;
    const int b = blockIdx.y;
    const int t = threadIdx.x;

    __shared__ int srow[Ss];
    __shared__ int scol[Ss];
    __shared__ unsigned int hist[NALL];
    __shared__ float4 coefs[Ss];

    if (t < NALL) hist[t] = 0u;
    __syncthreads();

    const int rf = rels[(b * Ss + i) * Ss + t];  // row i, col t
    const int rc = rels[(b * Ss + t) * Ss + i];  // row t, col i
    srow[t] = rf;
    scol[t] = rc;
    if (rf > 0) atomicAdd(&hist[rf], 1u);
    if (rc > 0) atomicAdd(&hist[rc + 32], 1u);
    __syncthreads();

    {
        float c0 = 0.f, c1 = 0.f, c2 = 0.f, c3 = 0.f;
        const int f = srow[t], c = scol[t];
        if (f > 0) {
            const float inv = 1.0f / (float)hist[f];
            const u16* w = relw + f * NBASIC;
            c0 += b2f(w[0]) * inv; c1 += b2f(w[1]) * inv;
            c2 += b2f(w[2]) * inv; c3 += b2f(w[3]) * inv;
        }
        if (c > 0) {
            const float inv = 1.0f / (float)hist[c + 32];
            const u16* w = relw + (c + 32) * NBASIC;
            c0 += b2f(w[0]) * inv; c1 += b2f(w[1]) * inv;
            c2 += b2f(w[2]) * inv; c3 += b2f(w[3]) * inv;
        }
        coefs[t] = make_float4(c0, c1, c2, c3);
    }
    __syncthreads();

    float acc[4][3] = {{0.f}};
    const u16* hb = h + b * Ss * Hh + t;
#pragma unroll 8
    for (int j = 0; j < Ss; ++j) {
        const float4 cf = coefs[j];
        const float h0 = b2f(hb[j * Hh]);
        const float h1 = b2f(hb[j * Hh + 256]);
        const float h2 = b2f(hb[j * Hh + 512]);
        acc[0][0] += cf.x * h0; acc[0][1] += cf.x * h1; acc[0][2] += cf.x * h2;
        acc[1][0] += cf.y * h0; acc[1][1] += cf.y * h1; acc[1][2] += cf.y * h2;
        acc[2][0] += cf.z * h0; acc[2][1] += cf.z * h1; acc[2][2] += cf.z * h2;
        acc[3][0] += cf.w * h0; acc[3][1] += cf.w * h1; acc[3][2] += cf.w * h2;
    }
#pragma unroll
    for (int k = 0; k < 4; ++k)
#pragma unroll
        for (int m = 0; m < 3; ++m)
            pooled[((b * 4 + k) * Ss + i) * Hh + t + m * 256] = f2b(acc[k][m]);
}

// ---- K2: out[b] = [pooled_0..3 | h] (256x3840) @ [basicT_0..3 ; selfW] (3840x768) ----
// bf16 MFMA 16x16x32, 64x64 tile, BK=64, reg prefetch across barrier.
__global__ __launch_bounds__(256) void k_out(const u16* __restrict__ h,
                                             const u16* __restrict__ pooled,
                                             const u16* __restrict__ basicT,
                                             const u16* __restrict__ selfw,
                                             const int* __restrict__ flag,
                                             void* __restrict__ outv) {
    constexpr int LDT = 72;  // pad 64->72: 16B-aligned rows, conflict-light
    __shared__ u16 As[64 * LDT];
    __shared__ u16 Bs[64 * LDT];

    const int b = blockIdx.z;
    const int i0 = blockIdx.y * 64;
    const int o0 = blockIdx.x * 64;
    const int t = threadIdx.x;
    const int row = t >> 2;       // 0..63
    const int kk = (t & 3) * 16;  // 0,16,32,48
    const int w = t >> 6;         // wave 0..3
    const int l = t & 63;
    const int quad = l >> 4;
    const int l16 = l & 15;
    const int bf = *flag;

    float4v acc[4];
#pragma unroll
    for (int c = 0; c < 4; ++c) acc[c] = (float4v){0.f, 0.f, 0.f, 0.f};

    auto aptr = [&](int s) -> const u16* {
        const int q = s / 12;
        const int kofs = (s % 12) * 64 + kk;
        if (q < 4) return pooled + (((b * 4 + q) * Ss) + i0 + row) * Hh + kofs;
        return h + (b * Ss + i0 + row) * Hh + kofs;
    };
    auto bptr = [&](int s) -> const u16* {
        const int q = s / 12;
        const int kofs = (s % 12) * 64 + kk;
        if (q < 4) return basicT + (q * Hh + o0 + row) * Hh + kofs;
        return selfw + (o0 + row) * Hh + kofs;
    };

    uint4 a0 = *(const uint4*)aptr(0);
    uint4 a1 = *(const uint4*)(aptr(0) + 8);
    uint4 bb0 = *(const uint4*)bptr(0);
    uint4 bb1 = *(const uint4*)(bptr(0) + 8);

    for (int s = 0; s < 60; ++s) {
        __syncthreads();
        *(uint4*)(&As[row * LDT + kk]) = a0;
        *(uint4*)(&As[row * LDT + kk + 8]) = a1;
        *(uint4*)(&Bs[row * LDT + kk]) = bb0;
        *(uint4*)(&Bs[row * LDT + kk + 8]) = bb1;
        __syncthreads();
        if (s + 1 < 60) {  // prefetch next tile while MFMAs run
            const u16* ap = aptr(s + 1);
            const u16* bp = bptr(s + 1);
            a0 = *(const uint4*)ap;  a1 = *(const uint4*)(ap + 8);
            bb0 = *(const uint4*)bp; bb1 = *(const uint4*)(bp + 8);
        }
#pragma unroll
        for (int k2 = 0; k2 < 64; k2 += 32) {
            const short8 af = *(const short8*)(&As[(16 * w + l16) * LDT + k2 + quad * 8]);
#pragma unroll
            for (int c = 0; c < 4; ++c) {
                const short8 bfr = *(const short8*)(&Bs[(16 * c + l16) * LDT + k2 + quad * 8]);
                acc[c] = __builtin_amdgcn_mfma_f32_16x16x32_bf16(af, bfr, acc[c], 0, 0, 0);
            }
        }
    }

    u16* out16 = (u16*)outv;
    float* out32 = (float*)outv;
#pragma unroll
    for (int c = 0; c < 4; ++c)
#pragma unroll
        for (int r = 0; r < 4; ++r) {
            const int il = 16 * w + quad * 4 + r;  // D row = (lane>>4)*4 + reg
            const int ol = 16 * c + l16;           // D col = lane & 15
            const int idx = (b * Ss + i0 + il) * Hh + o0 + ol;
            if (bf) out16[idx] = f2b(acc[c][r]);
            else    out32[idx] = acc[c][r];
        }
}

extern "C" void kernel_launch(void* const* d_in, const int* in_sizes, int n_in,
                              void* d_out, int out_size, void* d_ws, size_t ws_size,
                              hipStream_t stream) {
    const void* h_raw = d_in[0];                 // [4,256,768] fp32 or bf16
    const int* rels = (const int*)d_in[1];       // [4,256,256] i32
    const void* basic_raw = d_in[2];             // [4,768,768]
    const void* relw_raw = d_in[3];              // [64,4]
    const void* selfw_raw = d_in[4];             // [768,768] (out,in)

    // ws layout (u16 elements)
    u16* pooled = (u16*)d_ws;                               // 3,145,728
    u16* basicT = pooled + (size_t)Bb * 4 * Ss * Hh;        // 2,359,296
    u16* hbf    = basicT + (size_t)NBASIC * Hh * Hh;        //   786,432
    u16* swbf   = hbf + (size_t)Bb * Ss * Hh;               //   589,824
    u16* relwbf = swbf + (size_t)Hh * Hh;                   //       256
    int* flag   = (int*)(relwbf + 256);                     // 4B, 4-aligned

    k_detect<<<1, 256, 0, stream>>>((const u32*)h_raw, flag);
    k_cvt<<<(Bb * Ss * Hh + 255) / 256, 256, 0, stream>>>(h_raw, hbf, flag, Bb * Ss * Hh);
    k_cvt<<<(Hh * Hh + 255) / 256, 256, 0, stream>>>(selfw_raw, swbf, flag, Hh * Hh);
    k_cvt<<<1, 256, 0, stream>>>(relw_raw, relwbf, flag, NALL * NBASIC);
    k_transpose<<<dim3(24, 24, 4), dim3(32, 8), 0, stream>>>(basic_raw, basicT, flag);
    k_pooled<<<dim3(Ss, Bb), 256, 0, stream>>>(hbf, rels, relwbf, pooled);
    k_out<<<dim3(12, 4, 4), 256, 0, stream>>>(hbf, pooled, basicT, swbf, flag, d_out);
}

// Round 3
// 116.001 us; speedup vs baseline: 1.4125x; 1.4125x over previous
//
#include <hip/hip_runtime.h>
#include <stdint.h>

typedef unsigned short u16;
typedef unsigned int u32;
typedef __attribute__((ext_vector_type(8))) short short8;
typedef __attribute__((ext_vector_type(4))) float float4v;

#define Bb 4
#define Ss 256
#define Hh 768
#define NBASIC 4
#define NALL 64

__device__ __forceinline__ float b2f(u16 h) {
    u32 u = ((u32)h) << 16;
    float f;
    __builtin_memcpy(&f, &u, 4);
    return f;
}
__device__ __forceinline__ u16 f2b(float f) {
    u32 u;
    __builtin_memcpy(&u, &f, 4);
    u = (u + 0x7fffu + ((u >> 16) & 1u)) >> 16;  // RNE
    return (u16)u;
}

// dtype probe: low 16 bits of first 64 words of h. Packed-bf16 N(0,1) data
// has its bf16 exponent field in [100,140] ~always (count ~64/64); fp32 low
// mantissa bits are uniform (E[count]~10). Uniform scalar loads, no comms.
__device__ __forceinline__ int detect_bf16(const u32* __restrict__ hw) {
    int cnt = 0;
#pragma unroll
    for (int k = 0; k < 64; ++k) {
        const int e = (int)((hw[k] >> 7) & 0xFFu);
        cnt += (e >= 100 && e <= 140) ? 1 : 0;
    }
    return cnt >= 40;
}

// ---- K1: fused prep: cvt h, cvt selfw, basic->basicT, h->hT, coef build ----
// 1D grid of 256-thread blocks, region-decoded:
//   [0,3072)      h cvt -> hbf
//   [3072,5376)   selfw cvt -> swbf
//   [5376,7680)   basicT[q][o][i] = basic[q][i][o]   (24x24x4 tiles)
//   [7680,8448)   hT[b][o][j] = h[b][j][o]           (24x8x4 tiles)
//   [8448,9472)   coefC[b][k][i][j] build            (one block per (b,i))
__global__ __launch_bounds__(256) void k_prep(const void* __restrict__ h_raw,
                                              const void* __restrict__ basic_raw,
                                              const void* __restrict__ selfw_raw,
                                              const void* __restrict__ relw_raw,
                                              const int* __restrict__ rels,
                                              u16* __restrict__ hbf,
                                              u16* __restrict__ swbf,
                                              u16* __restrict__ basicT,
                                              u16* __restrict__ hT,
                                              u16* __restrict__ coefC) {
    __shared__ u16 tile[32][33];
    __shared__ float srelw[256];
    __shared__ u32 hist[NALL];

    const int blk = blockIdx.x;
    const int t = threadIdx.x;
    const int bf = detect_bf16((const u32*)h_raw);

    if (blk < 3072) {                       // h cvt
        const int i = blk * 256 + t;
        hbf[i] = bf ? ((const u16*)h_raw)[i] : f2b(((const float*)h_raw)[i]);
    } else if (blk < 5376) {                // selfw cvt
        const int i = (blk - 3072) * 256 + t;
        swbf[i] = bf ? ((const u16*)selfw_raw)[i] : f2b(((const float*)selfw_raw)[i]);
    } else if (blk < 7680) {                // basic transpose + cvt
        const int r = blk - 5376;
        const int o0 = (r % 24) * 32, i0 = ((r / 24) % 24) * 32, q = r / 576;
        const int tx = t & 31, ty = t >> 5;  // 32 x 8
        const size_t base = (size_t)q * Hh * Hh;
#pragma unroll
        for (int rr = 0; rr < 4; ++rr) {
            const size_t idx = base + (size_t)(i0 + ty + 8 * rr) * Hh + o0 + tx;
            tile[ty + 8 * rr][tx] = bf ? ((const u16*)basic_raw)[idx]
                                       : f2b(((const float*)basic_raw)[idx]);
        }
        __syncthreads();
#pragma unroll
        for (int rr = 0; rr < 4; ++rr)
            basicT[base + (size_t)(o0 + ty + 8 * rr) * Hh + i0 + tx] = tile[tx][ty + 8 * rr];
    } else if (blk < 8448) {                // h transpose -> hT[b][o][j]
        const int r = blk - 7680;
        const int o0 = (r % 24) * 32, i0 = ((r / 24) % 8) * 32, b = r / 192;
        const int tx = t & 31, ty = t >> 5;
#pragma unroll
        for (int rr = 0; rr < 4; ++rr) {
            const size_t idx = ((size_t)b * Ss + i0 + ty + 8 * rr) * Hh + o0 + tx;
            tile[ty + 8 * rr][tx] = bf ? ((const u16*)h_raw)[idx]
                                       : f2b(((const float*)h_raw)[idx]);
        }
        __syncthreads();
#pragma unroll
        for (int rr = 0; rr < 4; ++rr)
            hT[((size_t)b * Hh + o0 + ty + 8 * rr) * Ss + i0 + tx] = tile[tx][ty + 8 * rr];
    } else {                                // coef build: one block per (b,i)
        const int r = blk - 8448;
        const int i = r & 255, b = r >> 8;
        srelw[t] = bf ? b2f(((const u16*)relw_raw)[t]) : ((const float*)relw_raw)[t];
        if (t < NALL) hist[t] = 0u;
        __syncthreads();
        const int rf = rels[(b * Ss + i) * Ss + t];  // rels[b,i,t]
        const int rc = rels[(b * Ss + t) * Ss + i];  // rels[b,t,i]
        if (rf > 0) atomicAdd(&hist[rf], 1u);
        if (rc > 0) atomicAdd(&hist[rc + 32], 1u);
        __syncthreads();
        float c0 = 0.f, c1 = 0.f, c2 = 0.f, c3 = 0.f;
        if (rf > 0) {
            const float inv = 1.0f / (float)hist[rf];
            c0 += srelw[rf * 4 + 0] * inv; c1 += srelw[rf * 4 + 1] * inv;
            c2 += srelw[rf * 4 + 2] * inv; c3 += srelw[rf * 4 + 3] * inv;
        }
        if (rc > 0) {
            const int rr = rc + 32;
            const float inv = 1.0f / (float)hist[rr];
            c0 += srelw[rr * 4 + 0] * inv; c1 += srelw[rr * 4 + 1] * inv;
            c2 += srelw[rr * 4 + 2] * inv; c3 += srelw[rr * 4 + 3] * inv;
        }
        const size_t base = ((size_t)(b * 4) * Ss + i) * Ss + t;
        coefC[base]                    = f2b(c0);
        coefC[base + (size_t)Ss * Ss]     = f2b(c1);
        coefC[base + (size_t)2 * Ss * Ss] = f2b(c2);
        coefC[base + (size_t)3 * Ss * Ss] = f2b(c3);
    }
}

// ---- K2: pooled[b,k] (256x768) = coefC[b,k] (256x256) @ h[b] (256x768) ----
// A[m=i][kd=j]=coefC rows; B[n=o][kd=j]=hT rows. K=256 -> 4 iters of 64.
__global__ __launch_bounds__(256) void k_gemmP(const u16* __restrict__ coefC,
                                               const u16* __restrict__ hT,
                                               u16* __restrict__ pooled) {
    constexpr int LDT = 72;
    __shared__ u16 As[64 * LDT];
    __shared__ u16 Bs[64 * LDT];

    const int bk = blockIdx.z;  // b*4+k
    const int b = bk >> 2;
    const int i0 = blockIdx.y * 64;
    const int o0 = blockIdx.x * 64;
    const int t = threadIdx.x;
    const int row = t >> 2, kk = (t & 3) * 16;
    const int w = t >> 6, l = t & 63, quad = l >> 4, l16 = l & 15;

    float4v acc[4];
#pragma unroll
    for (int c = 0; c < 4; ++c) acc[c] = (float4v){0.f, 0.f, 0.f, 0.f};

    const u16* aB = coefC + ((size_t)bk * Ss + i0 + row) * Ss + kk;
    const u16* bB = hT + ((size_t)b * Hh + o0 + row) * Ss + kk;

    uint4 a0 = *(const uint4*)aB;
    uint4 a1 = *(const uint4*)(aB + 8);
    uint4 b0 = *(const uint4*)bB;
    uint4 b1 = *(const uint4*)(bB + 8);

    for (int s = 0; s < 4; ++s) {
        __syncthreads();
        *(uint4*)(&As[row * LDT + kk]) = a0;
        *(uint4*)(&As[row * LDT + kk + 8]) = a1;
        *(uint4*)(&Bs[row * LDT + kk]) = b0;
        *(uint4*)(&Bs[row * LDT + kk + 8]) = b1;
        __syncthreads();
        if (s + 1 < 4) {
            a0 = *(const uint4*)(aB + (s + 1) * 64);
            a1 = *(const uint4*)(aB + (s + 1) * 64 + 8);
            b0 = *(const uint4*)(bB + (s + 1) * 64);
            b1 = *(const uint4*)(bB + (s + 1) * 64 + 8);
        }
#pragma unroll
        for (int k2 = 0; k2 < 64; k2 += 32) {
            const short8 af = *(const short8*)(&As[(16 * w + l16) * LDT + k2 + quad * 8]);
#pragma unroll
            for (int c = 0; c < 4; ++c) {
                const short8 bfr = *(const short8*)(&Bs[(16 * c + l16) * LDT + k2 + quad * 8]);
                acc[c] = __builtin_amdgcn_mfma_f32_16x16x32_bf16(af, bfr, acc[c], 0, 0, 0);
            }
        }
    }

#pragma unroll
    for (int c = 0; c < 4; ++c)
#pragma unroll
        for (int r = 0; r < 4; ++r) {
            const int il = 16 * w + quad * 4 + r;
            const int ol = 16 * c + l16;
            pooled[((size_t)bk * Ss + i0 + il) * Hh + o0 + ol] = f2b(acc[c][r]);
        }
}

// ---- K3: partial[q][b] = A_q[b] (256x768) @ B_q (768x768), f32 partials ----
// q<4: A=pooled[b,q], B=basicT[q]; q==4: A=hbf[b], B=swbf. K=768 -> 12 iters.
__global__ __launch_bounds__(256) void k_gemmO(const u16* __restrict__ hbf,
                                               const u16* __restrict__ pooled,
                                               const u16* __restrict__ basicT,
                                               const u16* __restrict__ swbf,
                                               float* __restrict__ partial) {
    constexpr int LDT = 72;
    __shared__ u16 As[64 * LDT];
    __shared__ u16 Bs[64 * LDT];

    const int z = blockIdx.z;   // q*4+b
    const int b = z & 3, q = z >> 2;
    const int i0 = blockIdx.y * 64;
    const int o0 = blockIdx.x * 64;
    const int t = threadIdx.x;
    const int row = t >> 2, kk = (t & 3) * 16;
    const int w = t >> 6, l = t & 63, quad = l >> 4, l16 = l & 15;

    float4v acc[4];
#pragma unroll
    for (int c = 0; c < 4; ++c) acc[c] = (float4v){0.f, 0.f, 0.f, 0.f};

    const u16* aB = (q < 4) ? pooled + (((size_t)(b * 4 + q)) * Ss + i0 + row) * Hh + kk
                            : hbf + ((size_t)b * Ss + i0 + row) * Hh + kk;
    const u16* bB = (q < 4) ? basicT + ((size_t)q * Hh + o0 + row) * Hh + kk
                            : swbf + (size_t)(o0 + row) * Hh + kk;

    uint4 a0 = *(const uint4*)aB;
    uint4 a1 = *(const uint4*)(aB + 8);
    uint4 b0 = *(const uint4*)bB;
    uint4 b1 = *(const uint4*)(bB + 8);

    for (int s = 0; s < 12; ++s) {
        __syncthreads();
        *(uint4*)(&As[row * LDT + kk]) = a0;
        *(uint4*)(&As[row * LDT + kk + 8]) = a1;
        *(uint4*)(&Bs[row * LDT + kk]) = b0;
        *(uint4*)(&Bs[row * LDT + kk + 8]) = b1;
        __syncthreads();
        if (s + 1 < 12) {
            a0 = *(const uint4*)(aB + (s + 1) * 64);
            a1 = *(const uint4*)(aB + (s + 1) * 64 + 8);
            b0 = *(const uint4*)(bB + (s + 1) * 64);
            b1 = *(const uint4*)(bB + (s + 1) * 64 + 8);
        }
#pragma unroll
        for (int k2 = 0; k2 < 64; k2 += 32) {
            const short8 af = *(const short8*)(&As[(16 * w + l16) * LDT + k2 + quad * 8]);
#pragma unroll
            for (int c = 0; c < 4; ++c) {
                const short8 bfr = *(const short8*)(&Bs[(16 * c + l16) * LDT + k2 + quad * 8]);
                acc[c] = __builtin_amdgcn_mfma_f32_16x16x32_bf16(af, bfr, acc[c], 0, 0, 0);
            }
        }
    }

#pragma unroll
    for (int c = 0; c < 4; ++c)
#pragma unroll
        for (int r = 0; r < 4; ++r) {
            const int il = 16 * w + quad * 4 + r;
            const int ol = 16 * c + l16;
            partial[((size_t)z * Ss + i0 + il) * Hh + o0 + ol] = acc[c][r];
        }
}

// ---- K4: out = sum_q partial[q], epilogue dtype by inline detect ----
__global__ __launch_bounds__(256) void k_reduce(const float* __restrict__ partial,
                                                const void* __restrict__ h_raw,
                                                void* __restrict__ outv) {
    const int bf = detect_bf16((const u32*)h_raw);
    const size_t idx = ((size_t)blockIdx.x * 256 + threadIdx.x) * 4;
    const size_t slice = (size_t)Bb * Ss * Hh;  // 786432
    float4 s = *(const float4*)(partial + idx);
#pragma unroll
    for (int q = 1; q < 5; ++q) {
        const float4 p = *(const float4*)(partial + q * slice + idx);
        s.x += p.x; s.y += p.y; s.z += p.z; s.w += p.w;
    }
    if (bf) {
        const u32 lo = (u32)f2b(s.x) | ((u32)f2b(s.y) << 16);
        const u32 hi = (u32)f2b(s.z) | ((u32)f2b(s.w) << 16);
        *(uint2*)((u16*)outv + idx) = make_uint2(lo, hi);
    } else {
        *(float4*)((float*)outv + idx) = s;
    }
}

extern "C" void kernel_launch(void* const* d_in, const int* in_sizes, int n_in,
                              void* d_out, int out_size, void* d_ws, size_t ws_size,
                              hipStream_t stream) {
    const void* h_raw = d_in[0];             // [4,256,768]
    const int* rels = (const int*)d_in[1];   // [4,256,256] i32
    const void* basic_raw = d_in[2];         // [4,768,768]
    const void* relw_raw = d_in[3];          // [64,4]
    const void* selfw_raw = d_in[4];         // [768,768] (out,in)

    // ws layout (u16 elems; every array 16B-aligned)
    u16* pooled = (u16*)d_ws;                             // 3,145,728
    u16* basicT = pooled + (size_t)Bb * 4 * Ss * Hh;      // 2,359,296
    u16* hbf    = basicT + (size_t)NBASIC * Hh * Hh;      //   786,432
    u16* hT     = hbf + (size_t)Bb * Ss * Hh;             //   786,432
    u16* swbf   = hT + (size_t)Bb * Hh * Ss;              //   589,824
    u16* coefC  = swbf + (size_t)Hh * Hh;                 // 1,048,576
    float* partial = (float*)(coefC + (size_t)Bb * 4 * Ss * Ss);  // 3,932,160 f32

    k_prep<<<9472, 256, 0, stream>>>(h_raw, basic_raw, selfw_raw, relw_raw, rels,
                                     hbf, swbf, basicT, hT, coefC);
    k_gemmP<<<dim3(12, 4, 16), 256, 0, stream>>>(coefC, hT, pooled);
    k_gemmO<<<dim3(12, 4, 20), 256, 0, stream>>>(hbf, pooled, basicT, swbf, partial);
    k_reduce<<<768, 256, 0, stream>>>(partial, h_raw, d_out);
}